// Round 3
// baseline (839.631 us; speedup 1.0000x reference)
//
#include <hip/hip_runtime.h>
#include <math.h>

// Problem constants: B=1, C=64, D=H=W=16, HEADS=4, HD=16
#define CN   262144        // C * 4096 floats per [C, D, H, W] tensor

// ---------------------------------------------------------------------------
// Stage 1: spatial conv 3x3 over (H,W), per depth slice. pad (0,1,1).
__global__ __launch_bounds__(256) void conv_sp_kernel(
        const float* __restrict__ x, const float* __restrict__ w,
        const float* __restrict__ b, float* __restrict__ y) {
    __shared__ float ws[2304];          // 4 co x 576
    int cog = blockIdx.x >> 4;          // 0..15
    int d   = blockIdx.x & 15;
    int tid = threadIdx.x;
    for (int idx = tid; idx < 2304; idx += 256) ws[idx] = w[cog * 4 * 576 + idx];
    __syncthreads();
    int wv = tid >> 6;                  // wave -> co within group
    int co = cog * 4 + wv;
    int t  = tid & 63;
    int h  = t >> 2;
    int wq = t & 3;                     // w base = wq*4
    float bias = b[co];
    float ax = bias, ay = bias, az = bias, aw = bias;
    const float* wsc = ws + wv * 576;
    for (int ci = 0; ci < 64; ++ci) {
        const float* row = x + ci * 4096 + d * 256;
        const float* wc  = wsc + ci * 9;
        #pragma unroll
        for (int dh = 0; dh < 3; ++dh) {
            int hh = h + dh - 1;
            if (hh < 0 || hh > 15) continue;
            const float* r = row + hh * 16 + wq * 4;
            float4 q0 = *(const float4*)r;
            float lm = (wq > 0) ? r[-1] : 0.f;
            float rp = (wq < 3) ? r[4]  : 0.f;
            float wL = wc[dh * 3 + 0], wM = wc[dh * 3 + 1], wR = wc[dh * 3 + 2];
            ax += wL * lm   + wM * q0.x + wR * q0.y;
            ay += wL * q0.x + wM * q0.y + wR * q0.z;
            az += wL * q0.y + wM * q0.z + wR * q0.w;
            aw += wL * q0.z + wM * q0.w + wR * rp;
        }
    }
    float4 out = {ax, ay, az, aw};
    *(float4*)(y + co * 4096 + d * 256 + t * 4) = out;
}

// ---------------------------------------------------------------------------
// Stage 2: spectral conv, 3 taps over D. pad (1,0,0). float4 over positions.
__global__ __launch_bounds__(256) void conv_spec_kernel(
        const float* __restrict__ y1, const float* __restrict__ w,
        const float* __restrict__ b, float* __restrict__ y2) {
    __shared__ float ws[192];
    int co = blockIdx.x >> 2;
    int pb = blockIdx.x & 3;
    int tid = threadIdx.x;
    if (tid < 192) ws[tid] = w[co * 192 + tid];
    __syncthreads();
    int p0 = (pb * 256 + tid) * 4;      // float index, 4 consecutive positions
    int d  = p0 >> 8;
    float bias = b[co];
    float ax = bias, ay = bias, az = bias, aw = bias;
    for (int ci = 0; ci < 64; ++ci) {
        const float* base = y1 + ci * 4096 + p0;
        float w0 = ws[ci * 3], w1 = ws[ci * 3 + 1], w2 = ws[ci * 3 + 2];
        if (d > 0) {
            float4 a = *(const float4*)(base - 256);
            ax += w0 * a.x; ay += w0 * a.y; az += w0 * a.z; aw += w0 * a.w;
        }
        float4 m = *(const float4*)base;
        ax += w1 * m.x; ay += w1 * m.y; az += w1 * m.z; aw += w1 * m.w;
        if (d < 15) {
            float4 c = *(const float4*)(base + 256);
            ax += w2 * c.x; ay += w2 * c.y; az += w2 * c.z; aw += w2 * c.w;
        }
    }
    float4 out = {ax, ay, az, aw};
    *(float4*)(y2 + co * 4096 + p0) = out;
}

// ---------------------------------------------------------------------------
// Stage 3: 1x1x1 QKV conv -> transposed [head][pos][dim]; q pre-scaled 0.25.
__global__ __launch_bounds__(256) void qkv_kernel(
        const float* __restrict__ y2, const float* __restrict__ w,
        const float* __restrict__ b,
        float* __restrict__ qt, float* __restrict__ kt, float* __restrict__ vt) {
    __shared__ float ws[64];
    int oc = blockIdx.x >> 2;           // 0..191
    int pb = blockIdx.x & 3;
    int tid = threadIdx.x;
    if (tid < 64) ws[tid] = w[oc * 64 + tid];
    __syncthreads();
    int p0 = (pb * 256 + tid) * 4;
    float bias = b[oc];
    float ax = bias, ay = bias, az = bias, aw = bias;
    for (int ci = 0; ci < 64; ++ci) {
        float4 a = *(const float4*)(y2 + ci * 4096 + p0);
        float wc = ws[ci];
        ax += wc * a.x; ay += wc * a.y; az += wc * a.z; aw += wc * a.w;
    }
    int which = oc >> 6;                // 0=q 1=k 2=v
    int hd = oc & 63;
    int head = hd >> 4, dim = hd & 15;
    if (which == 0) { ax *= 0.25f; ay *= 0.25f; az *= 0.25f; aw *= 0.25f; }
    float* dst = (which == 0) ? qt : ((which == 1) ? kt : vt);
    dst += head * 65536 + p0 * 16 + dim;
    dst[0]  = ax; dst[16] = ay; dst[32] = az; dst[48] = aw;
}

// ---------------------------------------------------------------------------
// Stage 4: retention attention, shuffle-free softmax, m-split across blocks.
// Block = (head, i, j-quad, m-half) -> 64 queries x 8 m-slabs. 512 threads.
// Wave w: j = jq*4 + (w>>1); kq in (w&1)*8 + {qg*2, qg*2+1}.
// Lane = (qg=lane>>4, n=lane&15); lane owns full o-row for its n.
// Partial outputs (per m-half) summed in proj_kernel.
__global__ __launch_bounds__(512, 4) void attn_kernel(
        const float* __restrict__ qt, const float* __restrict__ kt,
        const float* __restrict__ vt, const float* __restrict__ gamma,
        float* __restrict__ ao0, float* __restrict__ ao1) {
    __shared__ float ksh[4160];         // 16 n x 260 padded rows
    __shared__ float vsh[4160];
    __shared__ float qsh[1024];         // 64 queries x 16 dims
    __shared__ float gp[32];
    int tid = threadIdx.x;
    int bI = blockIdx.x;
    int head = bI >> 7;                 // 4
    int i    = (bI >> 3) & 15;          // 16
    int jq   = (bI >> 1) & 3;           // 4
    int mh   = bI & 1;                  // 2

    if (tid < 32) {
        float g = 1.f / (1.f + __expf(-gamma[0]));
        gp[tid] = __powf(g, (float)tid);
    }
    if (tid < 256) {
        const float4* src = (const float4*)(qt + head * 65536 + (i * 256 + jq * 64) * 16);
        ((float4*)qsh)[tid] = src[tid];
    }
    __syncthreads();

    int wv   = tid >> 6;                // 0..7
    int lane = tid & 63;
    int qg   = lane >> 4;
    int n    = lane & 15;
    int j    = jq * 4 + (wv >> 1);
    int kq0  = (wv & 1) * 8 + qg * 2;   // query W coordinate (qq=0)
    int ql0  = (wv >> 1) * 16 + kq0;    // local query index in qsh

    float4 qreg[2][4];
    #pragma unroll
    for (int qq = 0; qq < 2; ++qq) {
        const float4* qs = (const float4*)(qsh + (ql0 + qq) * 16);
        #pragma unroll
        for (int r = 0; r < 4; ++r) qreg[qq][r] = qs[r];
    }
    float wdec[16];
    #pragma unroll
    for (int o = 0; o < 16; ++o) wdec[o] = gp[abs(n - o)];
    int ejk0 = abs(j - kq0);
    int ejk1 = abs(j - (kq0 + 1));

    float4 acc[2][4];
    #pragma unroll
    for (int qq = 0; qq < 2; ++qq)
        #pragma unroll
        for (int r = 0; r < 4; ++r) acc[qq][r] = make_float4(0.f, 0.f, 0.f, 0.f);

    const float* kbase = kt + head * 65536 + mh * 8 * 4096;
    const float* vbase = vt + head * 65536 + mh * 8 * 4096;

    for (int mm = 0; mm < 8; ++mm) {
        int m = mh * 8 + mm;
        __syncthreads();                // everyone done reading previous slab
        {
            const float4* ks = (const float4*)(kbase + mm * 4096);
            const float4* vs = (const float4*)(vbase + mm * 4096);
            #pragma unroll
            for (int u = 0; u < 2; ++u) {
                int c = tid + 512 * u;  // 0..1023
                int f = 4 * c;
                int nn = f >> 8;
                int col = f & 255;
                *(float4*)(ksh + nn * 260 + col) = ks[c];
                *(float4*)(vsh + nn * 260 + col) = vs[c];
            }
        }
        __syncthreads();

        float c0 = gp[abs(i - m) + ejk0];
        float c1 = gp[abs(i - m) + ejk1];
        float z[2][16];
        const float* krow = ksh + n * 260;
        #pragma unroll
        for (int o = 0; o < 16; ++o) {
            float4 k0 = *(const float4*)(krow + o * 16);
            float4 k1 = *(const float4*)(krow + o * 16 + 4);
            float4 k2 = *(const float4*)(krow + o * 16 + 8);
            float4 k3 = *(const float4*)(krow + o * 16 + 12);
            #pragma unroll
            for (int qq = 0; qq < 2; ++qq) {
                float4 a0 = qreg[qq][0], a1 = qreg[qq][1];
                float4 a2 = qreg[qq][2], a3 = qreg[qq][3];
                float dot = a0.x * k0.x + a0.y * k0.y + a0.z * k0.z + a0.w * k0.w
                          + a1.x * k1.x + a1.y * k1.y + a1.z * k1.z + a1.w * k1.w
                          + a2.x * k2.x + a2.y * k2.y + a2.z * k2.z + a2.w * k2.w
                          + a3.x * k3.x + a3.y * k3.y + a3.z * k3.z + a3.w * k3.w;
                z[qq][o] = dot * (qq ? c1 : c0) * wdec[o];
            }
        }
        #pragma unroll
        for (int qq = 0; qq < 2; ++qq) {
            float mx = z[qq][0];
            #pragma unroll
            for (int o = 1; o < 16; ++o) mx = fmaxf(mx, z[qq][o]);
            float sm = 0.f;
            #pragma unroll
            for (int o = 0; o < 16; ++o) {
                float e = __expf(z[qq][o] - mx);
                z[qq][o] = e;
                sm += e;
            }
            float inv = __builtin_amdgcn_rcpf(sm);
            #pragma unroll
            for (int o = 0; o < 16; ++o) z[qq][o] *= inv;
        }
        const float* vrow = vsh + n * 260;
        #pragma unroll
        for (int o = 0; o < 16; ++o) {
            float4 v0 = *(const float4*)(vrow + o * 16);
            float4 v1 = *(const float4*)(vrow + o * 16 + 4);
            float4 v2 = *(const float4*)(vrow + o * 16 + 8);
            float4 v3 = *(const float4*)(vrow + o * 16 + 12);
            #pragma unroll
            for (int qq = 0; qq < 2; ++qq) {
                float p = z[qq][o];
                acc[qq][0].x += p * v0.x; acc[qq][0].y += p * v0.y;
                acc[qq][0].z += p * v0.z; acc[qq][0].w += p * v0.w;
                acc[qq][1].x += p * v1.x; acc[qq][1].y += p * v1.y;
                acc[qq][1].z += p * v1.z; acc[qq][1].w += p * v1.w;
                acc[qq][2].x += p * v2.x; acc[qq][2].y += p * v2.y;
                acc[qq][2].z += p * v2.z; acc[qq][2].w += p * v2.w;
                acc[qq][3].x += p * v3.x; acc[qq][3].y += p * v3.y;
                acc[qq][3].z += p * v3.z; acc[qq][3].w += p * v3.w;
            }
        }
    }

    // reduce over the 16 n-lanes (xor butterfly stays within the 16-lane group)
    #pragma unroll
    for (int qq = 0; qq < 2; ++qq) {
        #pragma unroll
        for (int r = 0; r < 4; ++r) {
            #pragma unroll
            for (int s = 1; s < 16; s <<= 1) {
                acc[qq][r].x += __shfl_xor(acc[qq][r].x, s);
                acc[qq][r].y += __shfl_xor(acc[qq][r].y, s);
                acc[qq][r].z += __shfl_xor(acc[qq][r].z, s);
                acc[qq][r].w += __shfl_xor(acc[qq][r].w, s);
            }
        }
    }
    if (n == 0) {
        float* aop = mh ? ao1 : ao0;
        #pragma unroll
        for (int qq = 0; qq < 2; ++qq) {
            int p = i * 256 + j * 16 + kq0 + qq;
            float* base = aop + head * 16 * 4096 + p;
            #pragma unroll
            for (int r = 0; r < 4; ++r) {
                base[(4 * r + 0) * 4096] = acc[qq][r].x;
                base[(4 * r + 1) * 4096] = acc[qq][r].y;
                base[(4 * r + 2) * 4096] = acc[qq][r].z;
                base[(4 * r + 3) * 4096] = acc[qq][r].w;
            }
        }
    }
}

// ---------------------------------------------------------------------------
// Stage 5: 1x1x1 projection conv; sums the two m-half partials of attention.
__global__ __launch_bounds__(256) void proj_kernel(
        const float* __restrict__ ao0, const float* __restrict__ ao1,
        const float* __restrict__ w, const float* __restrict__ b,
        float* __restrict__ out) {
    __shared__ float ws[64];
    int oc = blockIdx.x >> 2;
    int pb = blockIdx.x & 3;
    int tid = threadIdx.x;
    if (tid < 64) ws[tid] = w[oc * 64 + tid];
    __syncthreads();
    int p0 = (pb * 256 + tid) * 4;
    float bias = b[oc];
    float ax = bias, ay = bias, az = bias, aw = bias;
    for (int ci = 0; ci < 64; ++ci) {
        float4 a = *(const float4*)(ao0 + ci * 4096 + p0);
        float4 c = *(const float4*)(ao1 + ci * 4096 + p0);
        float wc = ws[ci];
        ax += wc * (a.x + c.x); ay += wc * (a.y + c.y);
        az += wc * (a.z + c.z); aw += wc * (a.w + c.w);
    }
    float4 o4 = {ax, ay, az, aw};
    *(float4*)(out + oc * 4096 + p0) = o4;
}

// ---------------------------------------------------------------------------
extern "C" void kernel_launch(void* const* d_in, const int* in_sizes, int n_in,
                              void* d_out, int out_size, void* d_ws, size_t ws_size,
                              hipStream_t stream) {
    const float* x      = (const float*)d_in[0];
    const float* gamma  = (const float*)d_in[1];
    const float* w_sp   = (const float*)d_in[2];
    const float* b_sp   = (const float*)d_in[3];
    const float* w_spec = (const float*)d_in[4];
    const float* b_spec = (const float*)d_in[5];
    const float* w_qkv  = (const float*)d_in[6];
    const float* b_qkv  = (const float*)d_in[7];
    const float* w_proj = (const float*)d_in[8];
    const float* b_proj = (const float*)d_in[9];
    float* out = (float*)d_out;

    float* ws = (float*)d_ws;
    float* y1  = ws;            // [64][4096]
    float* y2  = ws + CN;       // [64][4096]
    float* qt  = ws + 2 * CN;   // [4][4096][16]
    float* kt  = ws + 3 * CN;   // [4][4096][16]
    float* vt  = ws + 4 * CN;   // [4][4096][16]
    float* ao0 = ws + 5 * CN;   // [64][4096] partial (m 0..7)
    float* ao1 = ws + 6 * CN;   // [64][4096] partial (m 8..15)

    conv_sp_kernel  <<<256, 256, 0, stream>>>(x, w_sp, b_sp, y1);
    conv_spec_kernel<<<256, 256, 0, stream>>>(y1, w_spec, b_spec, y2);
    qkv_kernel      <<<768, 256, 0, stream>>>(y2, w_qkv, b_qkv, qt, kt, vt);
    attn_kernel     <<<512, 512, 0, stream>>>(qt, kt, vt, gamma, ao0, ao1);
    proj_kernel     <<<256, 256, 0, stream>>>(ao0, ao1, w_proj, b_proj, out);
}

// Round 4
// 380.088 us; speedup vs baseline: 2.2090x; 2.2090x over previous
//
#include <hip/hip_runtime.h>
#include <math.h>

// Problem constants: B=1, C=64, D=H=W=16, HEADS=4, HD=16
#define CN   262144        // C * 4096 floats per [C, D, H, W] tensor

// ---------------------------------------------------------------------------
// Stage 1: spatial conv 3x3 over (H,W), per depth slice. pad (0,1,1).
__global__ __launch_bounds__(256) void conv_sp_kernel(
        const float* __restrict__ x, const float* __restrict__ w,
        const float* __restrict__ b, float* __restrict__ y) {
    __shared__ float ws[2304];          // 4 co x 576
    int cog = blockIdx.x >> 4;          // 0..15
    int d   = blockIdx.x & 15;
    int tid = threadIdx.x;
    for (int idx = tid; idx < 2304; idx += 256) ws[idx] = w[cog * 4 * 576 + idx];
    __syncthreads();
    int wv = tid >> 6;                  // wave -> co within group
    int co = cog * 4 + wv;
    int t  = tid & 63;
    int h  = t >> 2;
    int wq = t & 3;                     // w base = wq*4
    float bias = b[co];
    float ax = bias, ay = bias, az = bias, aw = bias;
    const float* wsc = ws + wv * 576;
    for (int ci = 0; ci < 64; ++ci) {
        const float* row = x + ci * 4096 + d * 256;
        const float* wc  = wsc + ci * 9;
        #pragma unroll
        for (int dh = 0; dh < 3; ++dh) {
            int hh = h + dh - 1;
            if (hh < 0 || hh > 15) continue;
            const float* r = row + hh * 16 + wq * 4;
            float4 q0 = *(const float4*)r;
            float lm = (wq > 0) ? r[-1] : 0.f;
            float rp = (wq < 3) ? r[4]  : 0.f;
            float wL = wc[dh * 3 + 0], wM = wc[dh * 3 + 1], wR = wc[dh * 3 + 2];
            ax += wL * lm   + wM * q0.x + wR * q0.y;
            ay += wL * q0.x + wM * q0.y + wR * q0.z;
            az += wL * q0.y + wM * q0.z + wR * q0.w;
            aw += wL * q0.z + wM * q0.w + wR * rp;
        }
    }
    float4 out = {ax, ay, az, aw};
    *(float4*)(y + co * 4096 + d * 256 + t * 4) = out;
}

// ---------------------------------------------------------------------------
// Stage 2: spectral conv, 3 taps over D. pad (1,0,0). float4 over positions.
__global__ __launch_bounds__(256) void conv_spec_kernel(
        const float* __restrict__ y1, const float* __restrict__ w,
        const float* __restrict__ b, float* __restrict__ y2) {
    __shared__ float ws[192];
    int co = blockIdx.x >> 2;
    int pb = blockIdx.x & 3;
    int tid = threadIdx.x;
    if (tid < 192) ws[tid] = w[co * 192 + tid];
    __syncthreads();
    int p0 = (pb * 256 + tid) * 4;      // float index, 4 consecutive positions
    int d  = p0 >> 8;
    float bias = b[co];
    float ax = bias, ay = bias, az = bias, aw = bias;
    for (int ci = 0; ci < 64; ++ci) {
        const float* base = y1 + ci * 4096 + p0;
        float w0 = ws[ci * 3], w1 = ws[ci * 3 + 1], w2 = ws[ci * 3 + 2];
        if (d > 0) {
            float4 a = *(const float4*)(base - 256);
            ax += w0 * a.x; ay += w0 * a.y; az += w0 * a.z; aw += w0 * a.w;
        }
        float4 m = *(const float4*)base;
        ax += w1 * m.x; ay += w1 * m.y; az += w1 * m.z; aw += w1 * m.w;
        if (d < 15) {
            float4 c = *(const float4*)(base + 256);
            ax += w2 * c.x; ay += w2 * c.y; az += w2 * c.z; aw += w2 * c.w;
        }
    }
    float4 out = {ax, ay, az, aw};
    *(float4*)(y2 + co * 4096 + p0) = out;
}

// ---------------------------------------------------------------------------
// Stage 3: 1x1x1 QKV conv -> transposed [head][pos][dim]; q pre-scaled 0.25.
__global__ __launch_bounds__(256) void qkv_kernel(
        const float* __restrict__ y2, const float* __restrict__ w,
        const float* __restrict__ b,
        float* __restrict__ qt, float* __restrict__ kt, float* __restrict__ vt) {
    __shared__ float ws[64];
    int oc = blockIdx.x >> 2;           // 0..191
    int pb = blockIdx.x & 3;
    int tid = threadIdx.x;
    if (tid < 64) ws[tid] = w[oc * 64 + tid];
    __syncthreads();
    int p0 = (pb * 256 + tid) * 4;
    float bias = b[oc];
    float ax = bias, ay = bias, az = bias, aw = bias;
    for (int ci = 0; ci < 64; ++ci) {
        float4 a = *(const float4*)(y2 + ci * 4096 + p0);
        float wc = ws[ci];
        ax += wc * a.x; ay += wc * a.y; az += wc * a.z; aw += wc * a.w;
    }
    int which = oc >> 6;                // 0=q 1=k 2=v
    int hd = oc & 63;
    int head = hd >> 4, dim = hd & 15;
    if (which == 0) { ax *= 0.25f; ay *= 0.25f; az *= 0.25f; aw *= 0.25f; }
    float* dst = (which == 0) ? qt : ((which == 1) ? kt : vt);
    dst += head * 65536 + p0 * 16 + dim;
    dst[0]  = ax; dst[16] = ay; dst[32] = az; dst[48] = aw;
}

// ---------------------------------------------------------------------------
// Stage 4: retention attention, shuffle-free softmax, m-split across blocks.
// Block = (head, i, j-quad, m-half) -> 64 queries x 8 m-slabs. 512 threads.
// __launch_bounds__(512, 2): 2 waves/EU -> VGPR cap 128 -> NO SPILLS.
// (512, 4) capped VGPRs at 64 and spilled z/acc to scratch: 2.1 GB HBM, 2.7x
// regression. Do not raise the occupancy request above 2.
__global__ __launch_bounds__(512, 2) void attn_kernel(
        const float* __restrict__ qt, const float* __restrict__ kt,
        const float* __restrict__ vt, const float* __restrict__ gamma,
        float* __restrict__ ao0, float* __restrict__ ao1) {
    __shared__ float ksh[4160];         // 16 n x 260 padded rows
    __shared__ float vsh[4160];
    __shared__ float qsh[1024];         // 64 queries x 16 dims
    __shared__ float gp[32];
    int tid = threadIdx.x;
    int bI = blockIdx.x;
    int head = bI >> 7;                 // 4
    int i    = (bI >> 3) & 15;          // 16
    int jq   = (bI >> 1) & 3;           // 4
    int mh   = bI & 1;                  // 2

    if (tid < 32) {
        float g = 1.f / (1.f + __expf(-gamma[0]));
        gp[tid] = __powf(g, (float)tid);
    }
    if (tid < 256) {
        const float4* src = (const float4*)(qt + head * 65536 + (i * 256 + jq * 64) * 16);
        ((float4*)qsh)[tid] = src[tid];
    }
    __syncthreads();

    int wv   = tid >> 6;                // 0..7
    int lane = tid & 63;
    int qg   = lane >> 4;
    int n    = lane & 15;
    int j    = jq * 4 + (wv >> 1);
    int kq0  = (wv & 1) * 8 + qg * 2;   // query W coordinate (qq=0)
    int ql0  = (wv >> 1) * 16 + kq0;    // local query index in qsh

    float4 qreg[2][4];
    #pragma unroll
    for (int qq = 0; qq < 2; ++qq) {
        const float4* qs = (const float4*)(qsh + (ql0 + qq) * 16);
        #pragma unroll
        for (int r = 0; r < 4; ++r) qreg[qq][r] = qs[r];
    }
    float wdec[16];
    #pragma unroll
    for (int o = 0; o < 16; ++o) wdec[o] = gp[abs(n - o)];
    int ejk0 = abs(j - kq0);
    int ejk1 = abs(j - (kq0 + 1));

    float4 acc[2][4];
    #pragma unroll
    for (int qq = 0; qq < 2; ++qq)
        #pragma unroll
        for (int r = 0; r < 4; ++r) acc[qq][r] = make_float4(0.f, 0.f, 0.f, 0.f);

    const float* kbase = kt + head * 65536 + mh * 8 * 4096;
    const float* vbase = vt + head * 65536 + mh * 8 * 4096;

    for (int mm = 0; mm < 8; ++mm) {
        int m = mh * 8 + mm;
        __syncthreads();                // everyone done reading previous slab
        {
            const float4* ks = (const float4*)(kbase + mm * 4096);
            const float4* vs = (const float4*)(vbase + mm * 4096);
            #pragma unroll
            for (int u = 0; u < 2; ++u) {
                int c = tid + 512 * u;  // 0..1023
                int f = 4 * c;
                int nn = f >> 8;
                int col = f & 255;
                *(float4*)(ksh + nn * 260 + col) = ks[c];
                *(float4*)(vsh + nn * 260 + col) = vs[c];
            }
        }
        __syncthreads();

        float c0 = gp[abs(i - m) + ejk0];
        float c1 = gp[abs(i - m) + ejk1];
        float z[2][16];
        const float* krow = ksh + n * 260;
        #pragma unroll
        for (int o = 0; o < 16; ++o) {
            float4 k0 = *(const float4*)(krow + o * 16);
            float4 k1 = *(const float4*)(krow + o * 16 + 4);
            float4 k2 = *(const float4*)(krow + o * 16 + 8);
            float4 k3 = *(const float4*)(krow + o * 16 + 12);
            #pragma unroll
            for (int qq = 0; qq < 2; ++qq) {
                float4 a0 = qreg[qq][0], a1 = qreg[qq][1];
                float4 a2 = qreg[qq][2], a3 = qreg[qq][3];
                float dot = a0.x * k0.x + a0.y * k0.y + a0.z * k0.z + a0.w * k0.w
                          + a1.x * k1.x + a1.y * k1.y + a1.z * k1.z + a1.w * k1.w
                          + a2.x * k2.x + a2.y * k2.y + a2.z * k2.z + a2.w * k2.w
                          + a3.x * k3.x + a3.y * k3.y + a3.z * k3.z + a3.w * k3.w;
                z[qq][o] = dot * (qq ? c1 : c0) * wdec[o];
            }
        }
        #pragma unroll
        for (int qq = 0; qq < 2; ++qq) {
            float mx = z[qq][0];
            #pragma unroll
            for (int o = 1; o < 16; ++o) mx = fmaxf(mx, z[qq][o]);
            float sm = 0.f;
            #pragma unroll
            for (int o = 0; o < 16; ++o) {
                float e = __expf(z[qq][o] - mx);
                z[qq][o] = e;
                sm += e;
            }
            float inv = __builtin_amdgcn_rcpf(sm);
            #pragma unroll
            for (int o = 0; o < 16; ++o) z[qq][o] *= inv;
        }
        const float* vrow = vsh + n * 260;
        #pragma unroll
        for (int o = 0; o < 16; ++o) {
            float4 v0 = *(const float4*)(vrow + o * 16);
            float4 v1 = *(const float4*)(vrow + o * 16 + 4);
            float4 v2 = *(const float4*)(vrow + o * 16 + 8);
            float4 v3 = *(const float4*)(vrow + o * 16 + 12);
            #pragma unroll
            for (int qq = 0; qq < 2; ++qq) {
                float p = z[qq][o];
                acc[qq][0].x += p * v0.x; acc[qq][0].y += p * v0.y;
                acc[qq][0].z += p * v0.z; acc[qq][0].w += p * v0.w;
                acc[qq][1].x += p * v1.x; acc[qq][1].y += p * v1.y;
                acc[qq][1].z += p * v1.z; acc[qq][1].w += p * v1.w;
                acc[qq][2].x += p * v2.x; acc[qq][2].y += p * v2.y;
                acc[qq][2].z += p * v2.z; acc[qq][2].w += p * v2.w;
                acc[qq][3].x += p * v3.x; acc[qq][3].y += p * v3.y;
                acc[qq][3].z += p * v3.z; acc[qq][3].w += p * v3.w;
            }
        }
    }

    // reduce over the 16 n-lanes (xor butterfly stays within the 16-lane group)
    #pragma unroll
    for (int qq = 0; qq < 2; ++qq) {
        #pragma unroll
        for (int r = 0; r < 4; ++r) {
            #pragma unroll
            for (int s = 1; s < 16; s <<= 1) {
                acc[qq][r].x += __shfl_xor(acc[qq][r].x, s);
                acc[qq][r].y += __shfl_xor(acc[qq][r].y, s);
                acc[qq][r].z += __shfl_xor(acc[qq][r].z, s);
                acc[qq][r].w += __shfl_xor(acc[qq][r].w, s);
            }
        }
    }
    if (n == 0) {
        float* aop = mh ? ao1 : ao0;
        #pragma unroll
        for (int qq = 0; qq < 2; ++qq) {
            int p = i * 256 + j * 16 + kq0 + qq;
            float* base = aop + head * 16 * 4096 + p;
            #pragma unroll
            for (int r = 0; r < 4; ++r) {
                base[(4 * r + 0) * 4096] = acc[qq][r].x;
                base[(4 * r + 1) * 4096] = acc[qq][r].y;
                base[(4 * r + 2) * 4096] = acc[qq][r].z;
                base[(4 * r + 3) * 4096] = acc[qq][r].w;
            }
        }
    }
}

// ---------------------------------------------------------------------------
// Stage 5: 1x1x1 projection conv; sums the two m-half partials of attention.
__global__ __launch_bounds__(256) void proj_kernel(
        const float* __restrict__ ao0, const float* __restrict__ ao1,
        const float* __restrict__ w, const float* __restrict__ b,
        float* __restrict__ out) {
    __shared__ float ws[64];
    int oc = blockIdx.x >> 2;
    int pb = blockIdx.x & 3;
    int tid = threadIdx.x;
    if (tid < 64) ws[tid] = w[oc * 64 + tid];
    __syncthreads();
    int p0 = (pb * 256 + tid) * 4;
    float bias = b[oc];
    float ax = bias, ay = bias, az = bias, aw = bias;
    for (int ci = 0; ci < 64; ++ci) {
        float4 a = *(const float4*)(ao0 + ci * 4096 + p0);
        float4 c = *(const float4*)(ao1 + ci * 4096 + p0);
        float wc = ws[ci];
        ax += wc * (a.x + c.x); ay += wc * (a.y + c.y);
        az += wc * (a.z + c.z); aw += wc * (a.w + c.w);
    }
    float4 o4 = {ax, ay, az, aw};
    *(float4*)(out + oc * 4096 + p0) = o4;
}

// ---------------------------------------------------------------------------
extern "C" void kernel_launch(void* const* d_in, const int* in_sizes, int n_in,
                              void* d_out, int out_size, void* d_ws, size_t ws_size,
                              hipStream_t stream) {
    const float* x      = (const float*)d_in[0];
    const float* gamma  = (const float*)d_in[1];
    const float* w_sp   = (const float*)d_in[2];
    const float* b_sp   = (const float*)d_in[3];
    const float* w_spec = (const float*)d_in[4];
    const float* b_spec = (const float*)d_in[5];
    const float* w_qkv  = (const float*)d_in[6];
    const float* b_qkv  = (const float*)d_in[7];
    const float* w_proj = (const float*)d_in[8];
    const float* b_proj = (const float*)d_in[9];
    float* out = (float*)d_out;

    float* ws = (float*)d_ws;
    float* y1  = ws;            // [64][4096]
    float* y2  = ws + CN;       // [64][4096]
    float* qt  = ws + 2 * CN;   // [4][4096][16]
    float* kt  = ws + 3 * CN;   // [4][4096][16]
    float* vt  = ws + 4 * CN;   // [4][4096][16]
    float* ao0 = ws + 5 * CN;   // [64][4096] partial (m 0..7)
    float* ao1 = ws + 6 * CN;   // [64][4096] partial (m 8..15)

    conv_sp_kernel  <<<256, 256, 0, stream>>>(x, w_sp, b_sp, y1);
    conv_spec_kernel<<<256, 256, 0, stream>>>(y1, w_spec, b_spec, y2);
    qkv_kernel      <<<768, 256, 0, stream>>>(y2, w_qkv, b_qkv, qt, kt, vt);
    attn_kernel     <<<512, 512, 0, stream>>>(qt, kt, vt, gamma, ao0, ao1);
    proj_kernel     <<<256, 256, 0, stream>>>(ao0, ao1, w_proj, b_proj, out);
}

// Round 5
// 228.342 us; speedup vs baseline: 3.6771x; 1.6646x over previous
//
#include <hip/hip_runtime.h>
#include <math.h>

// Problem constants: B=1, C=64, D=H=W=16, HEADS=4, HD=16
#define CN   262144        // C * 4096 floats per [C, D, H, W] tensor

typedef __attribute__((ext_vector_type(8))) short short8;   // 8 bf16 (4 VGPRs)
typedef __attribute__((ext_vector_type(4))) float float4v;  // MFMA C/D

static __device__ __forceinline__ unsigned short f2bf(float f) {
    union { float f; unsigned u; } v; v.f = f;
    unsigned r = (v.u + 0x7FFFu + ((v.u >> 16) & 1u)) >> 16;   // RNE
    return (unsigned short)r;
}

// ---------------------------------------------------------------------------
// Stage 1: spatial conv 3x3 over (H,W), per depth slice. pad (0,1,1).
__global__ __launch_bounds__(256) void conv_sp_kernel(
        const float* __restrict__ x, const float* __restrict__ w,
        const float* __restrict__ b, float* __restrict__ y) {
    __shared__ float ws[2304];          // 4 co x 576
    int cog = blockIdx.x >> 4;          // 0..15
    int d   = blockIdx.x & 15;
    int tid = threadIdx.x;
    for (int idx = tid; idx < 2304; idx += 256) ws[idx] = w[cog * 4 * 576 + idx];
    __syncthreads();
    int wv = tid >> 6;                  // wave -> co within group
    int co = cog * 4 + wv;
    int t  = tid & 63;
    int h  = t >> 2;
    int wq = t & 3;                     // w base = wq*4
    float bias = b[co];
    float ax = bias, ay = bias, az = bias, aw = bias;
    const float* wsc = ws + wv * 576;
    for (int ci = 0; ci < 64; ++ci) {
        const float* row = x + ci * 4096 + d * 256;
        const float* wc  = wsc + ci * 9;
        #pragma unroll
        for (int dh = 0; dh < 3; ++dh) {
            int hh = h + dh - 1;
            if (hh < 0 || hh > 15) continue;
            const float* r = row + hh * 16 + wq * 4;
            float4 q0 = *(const float4*)r;
            float lm = (wq > 0) ? r[-1] : 0.f;
            float rp = (wq < 3) ? r[4]  : 0.f;
            float wL = wc[dh * 3 + 0], wM = wc[dh * 3 + 1], wR = wc[dh * 3 + 2];
            ax += wL * lm   + wM * q0.x + wR * q0.y;
            ay += wL * q0.x + wM * q0.y + wR * q0.z;
            az += wL * q0.y + wM * q0.z + wR * q0.w;
            aw += wL * q0.z + wM * q0.w + wR * rp;
        }
    }
    float4 out = {ax, ay, az, aw};
    *(float4*)(y + co * 4096 + d * 256 + t * 4) = out;
}

// ---------------------------------------------------------------------------
// Stage 2: spectral conv, 3 taps over D. pad (1,0,0). float4 over positions.
__global__ __launch_bounds__(256) void conv_spec_kernel(
        const float* __restrict__ y1, const float* __restrict__ w,
        const float* __restrict__ b, float* __restrict__ y2) {
    __shared__ float ws[192];
    int co = blockIdx.x >> 2;
    int pb = blockIdx.x & 3;
    int tid = threadIdx.x;
    if (tid < 192) ws[tid] = w[co * 192 + tid];
    __syncthreads();
    int p0 = (pb * 256 + tid) * 4;      // float index, 4 consecutive positions
    int d  = p0 >> 8;
    float bias = b[co];
    float ax = bias, ay = bias, az = bias, aw = bias;
    for (int ci = 0; ci < 64; ++ci) {
        const float* base = y1 + ci * 4096 + p0;
        float w0 = ws[ci * 3], w1 = ws[ci * 3 + 1], w2 = ws[ci * 3 + 2];
        if (d > 0) {
            float4 a = *(const float4*)(base - 256);
            ax += w0 * a.x; ay += w0 * a.y; az += w0 * a.z; aw += w0 * a.w;
        }
        float4 m = *(const float4*)base;
        ax += w1 * m.x; ay += w1 * m.y; az += w1 * m.z; aw += w1 * m.w;
        if (d < 15) {
            float4 c = *(const float4*)(base + 256);
            ax += w2 * c.x; ay += w2 * c.y; az += w2 * c.z; aw += w2 * c.w;
        }
    }
    float4 out = {ax, ay, az, aw};
    *(float4*)(y2 + co * 4096 + p0) = out;
}

// ---------------------------------------------------------------------------
// Stage 3: 1x1x1 QKV conv -> bf16 MFMA-ready layouts.
//   qb/kb: [head][pos][d16] bf16 (q pre-scaled by 0.25)
//   vtb:   [head][m][npair=h>>1][dim][kappa32] bf16,
//          kappa = 8*(w>>2) + 4*(h&1) + (w&3)   (matches PV A-slot order)
__global__ __launch_bounds__(256) void qkv_kernel(
        const float* __restrict__ y2, const float* __restrict__ w,
        const float* __restrict__ b,
        unsigned short* __restrict__ qb, unsigned short* __restrict__ kb,
        unsigned short* __restrict__ vtb) {
    __shared__ float ws[64];
    int oc = blockIdx.x >> 2;           // 0..191
    int pb = blockIdx.x & 3;
    int tid = threadIdx.x;
    if (tid < 64) ws[tid] = w[oc * 64 + tid];
    __syncthreads();
    int p0 = (pb * 256 + tid) * 4;
    float bias = b[oc];
    float ax = bias, ay = bias, az = bias, aw = bias;
    for (int ci = 0; ci < 64; ++ci) {
        float4 a = *(const float4*)(y2 + ci * 4096 + p0);
        float wc = ws[ci];
        ax += wc * a.x; ay += wc * a.y; az += wc * a.z; aw += wc * a.w;
    }
    int which = oc >> 6;                // 0=q 1=k 2=v
    int hd = oc & 63;
    int head = hd >> 4, dim = hd & 15;
    if (which == 0) { ax *= 0.25f; ay *= 0.25f; az *= 0.25f; aw *= 0.25f; }
    if (which == 2) {
        int m = p0 >> 8, h = (p0 >> 4) & 15, w0 = p0 & 15;
        int kap = 8 * (w0 >> 2) + 4 * (h & 1);          // w0 % 4 == 0
        unsigned short* dst = vtb + ((head * 16 + m) * 8 + (h >> 1)) * 512
                                  + dim * 32 + kap;
        unsigned r0 = (unsigned)f2bf(ax) | ((unsigned)f2bf(ay) << 16);
        unsigned r1 = (unsigned)f2bf(az) | ((unsigned)f2bf(aw) << 16);
        *(unsigned*)(dst)     = r0;
        *(unsigned*)(dst + 2) = r1;
    } else {
        unsigned short* dst = (which == 0 ? qb : kb) + head * 65536 + p0 * 16 + dim;
        dst[0]  = f2bf(ax); dst[16] = f2bf(ay);
        dst[32] = f2bf(az); dst[48] = f2bf(aw);
    }
}

// ---------------------------------------------------------------------------
// Stage 4: retention attention via MFMA.
// Block = (head, m-quarter, q-octet): 8 waves, wave = one Q-tile (i,j, 16 w's).
// Per n-group (16 keys): D1[o][q] = mfma(A=K[o][d<16, padded], B=Q^T)   (K=32)
//   -> C/D layout col=lane&15=q, row=quad*4+reg=o  [measured m89]
//   -> decay*exp, sum over o (inlane + xor16/32), normalize
//   -> P sits directly in A-operand layout A[q][k=quad*8+j] [measured m118/120]
// PV: two n-groups packed per MFMA (kappa order, see qkv), O accumulates in C.
__global__ __launch_bounds__(512, 2) void attn_kernel(
        const unsigned short* __restrict__ qb, const unsigned short* __restrict__ kb,
        const unsigned short* __restrict__ vtb, const float* __restrict__ gamma,
        float* __restrict__ ao0, float* __restrict__ ao1,
        float* __restrict__ ao2, float* __restrict__ ao3) {
    __shared__ __align__(16) unsigned short ksh[4096];   // [n][o][d16] bf16, 8 KB
    __shared__ __align__(16) unsigned short vsh[4096];   // [np][dim][kappa32], 8 KB
    __shared__ float gp[32];
    int tid = threadIdx.x;
    int bI = blockIdx.x;
    int head = bI >> 7;                 // 4
    int mg   = (bI >> 5) & 3;           // 4 m-quarters
    int oct  = bI & 31;                 // 32 q-octets per head

    if (tid < 32) {
        float g = 1.f / (1.f + __expf(-gamma[0]));
        gp[tid] = __powf(g, (float)tid);
    }

    int wv = tid >> 6, lane = tid & 63;
    int quad = lane >> 4, l15 = lane & 15;
    int t = oct * 8 + wv;               // tile index 0..255 (= i*16 + j)
    int i = t >> 4, j = t & 15;

    short8 zero8 = {0, 0, 0, 0, 0, 0, 0, 0};
    float4v czero = {0.f, 0.f, 0.f, 0.f};

    // Q fragment (B operand): B[k=d][n=q]; zero for d>=16 (quads 2,3)
    short8 qf = zero8;
    if (quad < 2)
        qf = *(const short8*)(qb + head * 65536 + (t * 16 + l15) * 16 + quad * 8);

    __syncthreads();                    // gp ready
    float wd[4];
    #pragma unroll
    for (int r = 0; r < 4; ++r) wd[r] = gp[abs(l15 - (quad * 4 + r))];

    float4v O = czero;

    for (int mm = 0; mm < 4; ++mm) {
        int m = mg * 4 + mm;
        __syncthreads();                // previous slab fully consumed
        ((float4*)ksh)[tid] = ((const float4*)(kb  + head * 65536 + m * 4096))[tid];
        ((float4*)vsh)[tid] = ((const float4*)(vtb + (head * 16 + m) * 4096))[tid];
        __syncthreads();

        int eim = abs(i - m);
        #pragma unroll
        for (int np = 0; np < 8; ++np) {
            short8 a2 = zero8;
            #pragma unroll
            for (int s = 0; s < 2; ++s) {
                int n = np * 2 + s;
                short8 a1 = zero8;
                if (quad < 2)
                    a1 = *(const short8*)(ksh + n * 256 + l15 * 16 + quad * 8);
                float4v d1 = __builtin_amdgcn_mfma_f32_16x16x32_bf16(a1, qf, czero, 0, 0, 0);
                float smn = gp[eim + abs(j - n)];        // wave-uniform broadcast
                float e0 = __expf(d1[0] * smn * wd[0]);
                float e1 = __expf(d1[1] * smn * wd[1]);
                float e2 = __expf(d1[2] * smn * wd[2]);
                float e3 = __expf(d1[3] * smn * wd[3]);
                float sm = e0 + e1 + e2 + e3;
                sm += __shfl_xor(sm, 16);
                sm += __shfl_xor(sm, 32);
                float inv = __builtin_amdgcn_rcpf(sm);
                a2[s * 4 + 0] = (short)f2bf(e0 * inv);
                a2[s * 4 + 1] = (short)f2bf(e1 * inv);
                a2[s * 4 + 2] = (short)f2bf(e2 * inv);
                a2[s * 4 + 3] = (short)f2bf(e3 * inv);
            }
            short8 b2 = *(const short8*)(vsh + np * 512 + l15 * 32 + quad * 8);
            O = __builtin_amdgcn_mfma_f32_16x16x32_bf16(a2, b2, O, 0, 0, 0);
        }
    }

    // O: col=lane&15=dim, row=quad*4+reg=query-w. 4 consecutive positions.
    float* aop = (mg == 0) ? ao0 : ((mg == 1) ? ao1 : ((mg == 2) ? ao2 : ao3));
    float4 ov = {O[0], O[1], O[2], O[3]};
    *(float4*)(aop + (head * 16 + l15) * 4096 + t * 16 + quad * 4) = ov;
}

// ---------------------------------------------------------------------------
// Stage 5: 1x1x1 projection conv; sums the four m-quarter partials.
__global__ __launch_bounds__(256) void proj_kernel(
        const float* __restrict__ ao0, const float* __restrict__ ao1,
        const float* __restrict__ ao2, const float* __restrict__ ao3,
        const float* __restrict__ w, const float* __restrict__ b,
        float* __restrict__ out) {
    __shared__ float ws[64];
    int oc = blockIdx.x >> 2;
    int pb = blockIdx.x & 3;
    int tid = threadIdx.x;
    if (tid < 64) ws[tid] = w[oc * 64 + tid];
    __syncthreads();
    int p0 = (pb * 256 + tid) * 4;
    float bias = b[oc];
    float ax = bias, ay = bias, az = bias, aw = bias;
    for (int ci = 0; ci < 64; ++ci) {
        float4 a = *(const float4*)(ao0 + ci * 4096 + p0);
        float c = ws[ci];
        float4 d = *(const float4*)(ao1 + ci * 4096 + p0);
        float4 e = *(const float4*)(ao2 + ci * 4096 + p0);
        float4 f = *(const float4*)(ao3 + ci * 4096 + p0);
        ax += c * (a.x + d.x + e.x + f.x);
        ay += c * (a.y + d.y + e.y + f.y);
        az += c * (a.z + d.z + e.z + f.z);
        aw += c * (a.w + d.w + e.w + f.w);
    }
    float4 o4 = {ax, ay, az, aw};
    *(float4*)(out + oc * 4096 + p0) = o4;
}

// ---------------------------------------------------------------------------
extern "C" void kernel_launch(void* const* d_in, const int* in_sizes, int n_in,
                              void* d_out, int out_size, void* d_ws, size_t ws_size,
                              hipStream_t stream) {
    const float* x      = (const float*)d_in[0];
    const float* gamma  = (const float*)d_in[1];
    const float* w_sp   = (const float*)d_in[2];
    const float* b_sp   = (const float*)d_in[3];
    const float* w_spec = (const float*)d_in[4];
    const float* b_spec = (const float*)d_in[5];
    const float* w_qkv  = (const float*)d_in[6];
    const float* b_qkv  = (const float*)d_in[7];
    const float* w_proj = (const float*)d_in[8];
    const float* b_proj = (const float*)d_in[9];
    float* out = (float*)d_out;

    float* ws = (float*)d_ws;
    float* y1  = ws;                         // [64][4096] f32; reused as ao0
    float* y2  = ws + CN;                    // [64][4096] f32; reused as ao1
    unsigned short* qb  = (unsigned short*)(ws + 2 * CN);            // 512 KB bf16
    unsigned short* kb  = (unsigned short*)(ws + 2 * CN + CN / 2);   // 512 KB bf16
    unsigned short* vtb = (unsigned short*)(ws + 3 * CN);            // 512 KB bf16
    float* ao2 = ws + 3 * CN + CN / 2;       // [64][4096] partial (m 8..11)
    float* ao3 = ws + 4 * CN + CN / 2;       // [64][4096] partial (m 12..15)
    float* ao0 = y1;                         // safe: y1 consumed by conv_spec
    float* ao1 = y2;                         // safe: y2 consumed by qkv

    conv_sp_kernel  <<<256, 256, 0, stream>>>(x, w_sp, b_sp, y1);
    conv_spec_kernel<<<256, 256, 0, stream>>>(y1, w_spec, b_spec, y2);
    qkv_kernel      <<<768, 256, 0, stream>>>(y2, w_qkv, b_qkv, qb, kb, vtb);
    attn_kernel     <<<512, 512, 0, stream>>>(qb, kb, vtb, gamma, ao0, ao1, ao2, ao3);
    proj_kernel     <<<256, 256, 0, stream>>>(ao0, ao1, ao2, ao3, w_proj, b_proj, out);
}